// Round 1
// 1067.225 us; speedup vs baseline: 1.0043x; 1.0043x over previous
//
#include <hip/hip_runtime.h>
#include <math.h>

#define B   32
#define H   16
#define DK  64
#define DM  1024
#define TC  4096
#define NS  8            // T splits in flash-decode
#define DSL 8            // d-slices in projection split-K
#define LOG2E 1.44269504088896340736f
#define SCALE 0.125f     // 1/sqrt(DK)

// ---------------------------------------------------------------------------
// Projection partial: part[(m*DSL+ds)][j][b] = sum_{d in slice} in[b][d]*w[j][d]
// Block: (jt, ds, m), 256 threads. in tile (32 b x 128 d) staged in LDS,
// b mapped to lanes -> weight loads are half-wave broadcasts, reduction is
// serial in-thread over d (no shuffles, no atomics).
// ---------------------------------------------------------------------------
__global__ __launch_bounds__(256) void proj_partial(
    const float* __restrict__ in,     // [32][1024]
    const float* __restrict__ w0,
    const float* __restrict__ w1,
    const float* __restrict__ w2,
    float* __restrict__ part)         // [(m*DSL+ds)][1024][32]
{
    const int jt = blockIdx.x;        // 0..15 (64 j per block)
    const int ds = blockIdx.y;        // 0..7  (128 d per slice)
    const int m  = blockIdx.z;
    const float* __restrict__ w = (m == 0) ? w0 : (m == 1) ? w1 : w2;

    __shared__ float qs[32 * 132];    // 32 rows x 128 d, padded to 132
    const float4* in4 = (const float4*)in;
    float4* qs4 = (float4*)qs;
    const int tid = threadIdx.x;

    #pragma unroll
    for (int k = 0; k < 4; k++) {
        int g   = tid + k * 256;      // 0..1023 float4s
        int b   = g >> 5;
        int dd4 = g & 31;
        qs4[b * 33 + dd4] = in4[b * 256 + ds * 32 + dd4];
    }
    __syncthreads();

    const int wave  = tid >> 6;
    const int lane  = tid & 63;
    const int jhalf = lane >> 5;      // which j of the pair
    const int b     = lane & 31;      // batch across lanes
    const float4* w4 = (const float4*)w;

    #pragma unroll
    for (int p = 0; p < 8; p++) {
        int j = jt * 64 + wave * 16 + p * 2 + jhalf;
        float acc = 0.f;
        #pragma unroll
        for (int it = 0; it < 32; it++) {
            float4 wv = w4[j * 256 + ds * 32 + it];   // broadcast per half-wave
            float4 qv = qs4[b * 33 + it];             // conflict-free (33 stride)
            acc += wv.x * qv.x + wv.y * qv.y + wv.z * qv.z + wv.w * qv.w;
        }
        part[((m * DSL + ds) * DM + j) * 32 + b] = acc;  // coalesced (b fastest)
    }
}

// ---------------------------------------------------------------------------
// Sum the DSL partials + bias. out[m][b][1024].
// ---------------------------------------------------------------------------
__global__ __launch_bounds__(256) void reduce_part(
    const float* __restrict__ part,
    const float* __restrict__ b0,
    const float* __restrict__ b1,
    const float* __restrict__ b2,
    float* __restrict__ out)
{
    const int gid = blockIdx.x * 256 + threadIdx.x;
    const int m = gid >> 15;          // /32768
    const int r = gid & 32767;        // j*32 + b
    const int j = r >> 5;
    const int b = r & 31;
    float s = 0.f;
    #pragma unroll
    for (int ds = 0; ds < DSL; ds++)
        s += part[(m * DSL + ds) * (DM * 32) + r];
    const float* __restrict__ bias = (m == 0) ? b0 : (m == 1) ? b1 : b2;
    out[m * (B * DM) + b * DM + j] = s + bias[j];
}

// ---------------------------------------------------------------------------
// Flash-decode partition, single-pass online softmax.
// Block (split,h,b): 4 waves, each wave owns 128 of the 512 rows.
// Per iteration a wave loads K AND V for the same 4 rows (interleaved streams,
// 2 KB/wave-iter in flight), computes the score via 4 shfl_xor, and updates a
// register-resident running (m, l, acc[4]) — no score buffer in LDS, exactly
// ONE __syncthreads() at the end for the 4-wave merge.
// ---------------------------------------------------------------------------
__global__ __launch_bounds__(256) void attn_part_kernel(
    const float* __restrict__ qh,     // [B][H*DK]
    const float* __restrict__ Kc,     // [B][H][TC][DK]
    const float* __restrict__ Vc,
    float* __restrict__ part_O,       // [bh][NS][64]
    float* __restrict__ part_ml)      // [bh][NS][2]
{
    const int split = blockIdx.x;
    const int h = blockIdx.y;
    const int b = blockIdx.z;
    const int bh = b * H + h;
    const int t0 = split * (TC / NS);   // 512-row chunk

    __shared__ float so[4 * 64];        // per-wave O
    __shared__ float sml[8];            // per-wave (m,l)

    const int tid  = threadIdx.x;
    const int wave = tid >> 6;
    const int lane = tid & 63;
    const int r = lane >> 4;            // row slot 0..3 within wave
    const int c = lane & 15;            // float4 column (64 d = 16 float4)

    const float4 q4 = ((const float4*)(qh + b * DM + h * DK))[c];
    const float4* K4 = (const float4*)(Kc + (size_t)bh * TC * DK);
    const float4* V4 = (const float4*)(Vc + (size_t)bh * TC * DK);
    const float sc = SCALE * LOG2E;

    float m = -1e30f;
    float l = 0.f;
    float4 acc = make_float4(0.f, 0.f, 0.f, 0.f);

    const int base = t0 + wave * 128;   // this wave's 128 rows

    #pragma unroll 4
    for (int it = 0; it < 32; it++) {
        int t = base + it * 4 + r;
        float4 k4 = K4[t * 16 + c];     // 4 rows x 1 KB, fully coalesced
        float4 v4 = V4[t * 16 + c];     // same rows, issued alongside K
        float d = q4.x * k4.x + q4.y * k4.y + q4.z * k4.z + q4.w * k4.w;
        d += __shfl_xor(d, 1);
        d += __shfl_xor(d, 2);
        d += __shfl_xor(d, 4);
        d += __shfl_xor(d, 8);          // all 16 lanes of group r hold the score
        float s = d * sc;
        float mo = m;
        m = fmaxf(m, s);
        float f = exp2f(mo - m);        // 1.0 when max unchanged
        float p = exp2f(s - m);
        l = l * f + p;
        acc.x = acc.x * f + p * v4.x;
        acc.y = acc.y * f + p * v4.y;
        acc.z = acc.z * f + p * v4.z;
        acc.w = acc.w * f + p * v4.w;
    }

    // merge the 4 row-groups inside the wave (lanes with equal c hold the
    // same d-columns, so acc slices align across groups)
    #pragma unroll
    for (int off = 16; off <= 32; off <<= 1) {
        float mo = __shfl_xor(m, off);
        float lo = __shfl_xor(l, off);
        float ax = __shfl_xor(acc.x, off);
        float ay = __shfl_xor(acc.y, off);
        float az = __shfl_xor(acc.z, off);
        float aw = __shfl_xor(acc.w, off);
        float M  = fmaxf(m, mo);
        float fs = exp2f(m - M);
        float fo = exp2f(mo - M);
        m = M;
        l = l * fs + lo * fo;
        acc.x = acc.x * fs + ax * fo;
        acc.y = acc.y * fs + ay * fo;
        acc.z = acc.z * fs + az * fo;
        acc.w = acc.w * fs + aw * fo;
    }

    // one barrier: 4 waves -> block partial
    if (lane < 16) {
        ((float4*)&so[wave * 64])[c] = acc;
        if (c == 0) { sml[wave * 2] = m; sml[wave * 2 + 1] = l; }
    }
    __syncthreads();

    if (tid < 64) {
        const float M = fmaxf(fmaxf(sml[0], sml[2]), fmaxf(sml[4], sml[6]));
        float L = 0.f, od = 0.f;
        #pragma unroll
        for (int w = 0; w < 4; w++) {
            float f = exp2f(sml[w * 2] - M);
            L  += sml[w * 2 + 1] * f;
            od += so[w * 64 + tid] * f;
        }
        part_O[(bh * NS + split) * 64 + tid] = od;
        if (tid == 0) {
            part_ml[(bh * NS + split) * 2 + 0] = M;
            part_ml[(bh * NS + split) * 2 + 1] = L;
        }
    }
}

// ---------------------------------------------------------------------------
// Merge NS partials + the freshly-projected token (m=s_new, l=1, O=v_new).
// One wave per (b,h). x[b][h*64+d] = O/L.
// ---------------------------------------------------------------------------
__global__ __launch_bounds__(64) void combine_kernel(
    const float* __restrict__ qh,
    const float* __restrict__ kn,
    const float* __restrict__ vn,
    const float* __restrict__ part_O,
    const float* __restrict__ part_ml,
    float* __restrict__ x)
{
    const int bh = blockIdx.x;
    const int b = bh >> 4;
    const int h = bh & 15;
    const int d = threadIdx.x;
    const int off = b * DM + h * DK + d;

    const float qv = qh[off];
    const float kv = kn[off];
    const float vv = vn[off];

    float s = qv * kv;
    s += __shfl_xor(s, 1);
    s += __shfl_xor(s, 2);
    s += __shfl_xor(s, 4);
    s += __shfl_xor(s, 8);
    s += __shfl_xor(s, 16);
    s += __shfl_xor(s, 32);
    const float snew = s * (SCALE * LOG2E);

    float mvals[NS], lvals[NS];
    float M = snew;
    #pragma unroll
    for (int i = 0; i < NS; i++) {
        mvals[i] = part_ml[(bh * NS + i) * 2 + 0];
        lvals[i] = part_ml[(bh * NS + i) * 2 + 1];
        M = fmaxf(M, mvals[i]);
    }
    const float wn = exp2f(snew - M);
    float L = wn;
    float od = vv * wn;
    #pragma unroll
    for (int i = 0; i < NS; i++) {
        float wgt = exp2f(mvals[i] - M);
        L += lvals[i] * wgt;
        od += part_O[(bh * NS + i) * 64 + d] * wgt;
    }
    x[bh * 64 + d] = od / L;   // bh*64 == b*1024 + h*64
}

// ---------------------------------------------------------------------------
extern "C" void kernel_launch(void* const* d_in, const int* in_sizes, int n_in,
                              void* d_out, int out_size, void* d_ws, size_t ws_size,
                              hipStream_t stream) {
    const float* q  = (const float*)d_in[0];
    const float* Kc = (const float*)d_in[1];
    const float* Vc = (const float*)d_in[2];
    const float* wq = (const float*)d_in[3];
    const float* bq = (const float*)d_in[4];
    const float* wk = (const float*)d_in[5];
    const float* bk = (const float*)d_in[6];
    const float* wv = (const float*)d_in[7];
    const float* bv = (const float*)d_in[8];
    const float* wo = (const float*)d_in[9];
    const float* bo = (const float*)d_in[10];
    float* out = (float*)d_out;
    float* ws = (float*)d_ws;

    // workspace layout (floats)
    float* part   = ws;                       // 3*8*32768  = 786432
    float* qkv    = ws + 786432;              // 3*32768    =  98304 (qh,kn,vn)
    float* partO  = ws + 786432 + 98304;      // 512*8*64   = 262144
    float* partml = ws + 786432 + 98304 + 262144;          //  8192
    float* x      = ws + 786432 + 98304 + 262144 + 8192;   // 32768
    float* qh = qkv;
    float* kn = qkv + 32768;
    float* vn = qkv + 65536;

    // 1) QKV projections (split-K partials, then reduce+bias)
    proj_partial<<<dim3(16, DSL, 3), 256, 0, stream>>>(q, wq, wk, wv, part);
    reduce_part<<<dim3(3 * 32768 / 256), 256, 0, stream>>>(part, bq, bk, bv, qkv);

    // 2) flash-decode over the 4096 cached positions (single-pass online softmax)
    attn_part_kernel<<<dim3(NS, H, B), 256, 0, stream>>>(qh, Kc, Vc, partO, partml);

    // 3) merge partials + new token
    combine_kernel<<<dim3(B * H), 64, 0, stream>>>(qh, kn, vn, partO, partml, x);

    // 4) output projection
    proj_partial<<<dim3(16, DSL, 1), 256, 0, stream>>>(x, wo, wo, wo, part);
    reduce_part<<<dim3(32768 / 256), 256, 0, stream>>>(part, bo, bo, bo, out);
}